// Round 4
// baseline (132.262 us; speedup 1.0000x reference)
//
#include <hip/hip_runtime.h>

#define C_IN     7
#define D_MODEL  512
#define TAO      3
#define M_TAPS   5
#define KERNELS  73            // D_MODEL / C_IN
#define B_SZ     32
#define L_SZ     4096
#define TB       256           // t-positions per block
#define NTB      (L_SZ / TB)   // 16
#define ROWS     (TB + 17)     // 273 staged rows (16 back-halo + 1 forward)
#define RPAD     276

__global__ __launch_bounds__(512, 4) void trc_conv_kernel(
    const float* __restrict__ x,          // [B, L, C_IN]
    const float* __restrict__ conv_w,     // [73, 6, 3]
    const float* __restrict__ conv_b,     // [73]
    const float* __restrict__ leftout_w,  // [1, 6, 3]
    const float* __restrict__ leftout_b,  // [1]
    float* __restrict__ out)              // [B, L, 512]
{
    __shared__ float xs[C_IN][RPAD];
    const int tid = threadIdx.x;
    const int b   = blockIdx.x / NTB;
    const int tb  = blockIdx.x % NTB;
    const int t0  = tb * TB;

    // Stage x rows [t0-16, t0+TB] (circular) into LDS, transposed [ch][row].
    const float* xb = x + (size_t)b * L_SZ * C_IN;
    for (int i = tid; i < ROWS * C_IN; i += 512) {
        int r = i / C_IN, c = i - r * C_IN;
        int g = t0 - 16 + r;
        if (g < 0)      g += L_SZ;
        if (g >= L_SZ)  g -= L_SZ;
        xs[c][r] = xb[(size_t)g * C_IN + c];
    }
    __syncthreads();

    // Per-thread output column d: ch = d/73, o = d%73 (d==511 -> leftout).
    const int d = tid;
    int ch;
    const float* wsrc;
    float bias;
    if (d < C_IN * KERNELS) {
        ch = d / KERNELS;
        int o = d - ch * KERNELS;
        wsrc = conv_w + o * 18;
        bias = conv_b[o];
    } else {
        ch = C_IN - 1;
        wsrc = leftout_w;
        bias = leftout_b[0];
    }
    const float* __restrict__ row = &xs[ch][0];

    // FIR weights by row-offset j (0 = oldest = row t-16): k=j%3, m=(15+k-j)/3.
    float wreg[18];
    #pragma unroll
    for (int j = 0; j < 18; ++j) {
        int k = j % 3;
        int m = (15 + k - j) / 3;
        wreg[j] = wsrc[m * 3 + k];
    }

    float* outp = out + ((size_t)b * L_SZ + t0) * D_MODEL + d;

    // Fast region: t in [16, 4094]  ->  tl in [lo, tl_hi)
    const int lo    = (tb == 0)       ? 16      : 0;
    const int tl_hi = (tb == NTB - 1) ? TB - 1  : TB;

    // ---- masked prologue (only tile 0: tl in [0,16)) ----
    if (tb == 0) {
        for (int tl = 0; tl < 16; ++tl) {
            float acc = bias;
            #pragma unroll
            for (int k = 0; k < 3; ++k) {
                int tt = t0 + tl + k - 1;
                if (tt < 0)      tt += L_SZ;
                if (tt >= L_SZ)  tt -= L_SZ;
                if (tt >= M_TAPS * TAO) {
                    int lt = tl + 15 + k;
                    #pragma unroll
                    for (int m = 0; m < 6; ++m)
                        acc = fmaf(row[lt - 3 * m], wreg[15 + k - 3 * m], acc);
                }
            }
            outp[(size_t)tl * D_MODEL] = acc;
        }
    }

    // ---- fast region, chunked sliding window: 16 outputs / chunk ----
    // Invariant at chunk start c: win[q] = row[c+q], q=0..16.
    float win[33];
    #pragma unroll
    for (int i = 0; i < 17; ++i) win[i] = row[lo + i];

    const int c_end = lo + ((tl_hi - lo) & ~15);   // end of full chunks
    for (int c = lo; c < c_end; c += 16) {
        #pragma unroll
        for (int i = 0; i < 16; ++i) win[17 + i] = row[c + 17 + i];
        #pragma unroll
        for (int i = 0; i < 16; ++i) {
            float acc = bias;
            #pragma unroll
            for (int j = 0; j < 18; ++j)
                acc = fmaf(win[i + j], wreg[j], acc);
            outp[(size_t)(c + i) * D_MODEL] = acc;
        }
        #pragma unroll
        for (int i = 0; i < 17; ++i) win[i] = win[i + 16];
    }

    // ---- fast leftovers (last tile only: tl in [c_end, tl_hi)) ----
    for (int tl = c_end; tl < tl_hi; ++tl) {
        float acc = bias;
        #pragma unroll
        for (int j = 0; j < 18; ++j)
            acc = fmaf(row[tl + j], wreg[j], acc);
        outp[(size_t)tl * D_MODEL] = acc;
    }

    // ---- masked epilogue (last tile only: tl = TB-1, t = 4095) ----
    if (tb == NTB - 1) {
        const int tl = TB - 1;
        float acc = bias;
        #pragma unroll
        for (int k = 0; k < 3; ++k) {
            int tt = t0 + tl + k - 1;
            if (tt < 0)      tt += L_SZ;
            if (tt >= L_SZ)  tt -= L_SZ;
            if (tt >= M_TAPS * TAO) {
                int lt = tl + 15 + k;
                #pragma unroll
                for (int m = 0; m < 6; ++m)
                    acc = fmaf(row[lt - 3 * m], wreg[15 + k - 3 * m], acc);
            }
        }
        outp[(size_t)tl * D_MODEL] = acc;
    }
}

extern "C" void kernel_launch(void* const* d_in, const int* in_sizes, int n_in,
                              void* d_out, int out_size, void* d_ws, size_t ws_size,
                              hipStream_t stream) {
    const float* x          = (const float*)d_in[0];
    const float* conv_w     = (const float*)d_in[1];
    const float* conv_b     = (const float*)d_in[2];
    const float* leftout_w  = (const float*)d_in[3];
    const float* leftout_b  = (const float*)d_in[4];
    float* out = (float*)d_out;

    dim3 grid(B_SZ * NTB);   // 512 blocks = 2 per CU
    trc_conv_kernel<<<grid, 512, 0, stream>>>(x, conv_w, conv_b,
                                              leftout_w, leftout_b, out);
}

// Round 5
// 51.522 us; speedup vs baseline: 2.5671x; 2.5671x over previous
//
#include <hip/hip_runtime.h>

#define C_IN     7
#define D_MODEL  512
#define TAO      3
#define M_TAPS   5
#define KERNELS  73            // D_MODEL / C_IN
#define B_SZ     32
#define L_SZ     4096
#define TB       64            // t-positions per block
#define NTB      (L_SZ / TB)   // 64
#define ROWS     (TB + 17)     // 81 staged rows (16 back-halo + 1 forward)
#define RPAD     84
#define CHUNK    8             // t-rows per coop-store chunk
#define NCHUNK   (TB / CHUNK)  // 8

__global__ __launch_bounds__(512, 4) void trc_conv_kernel(
    const float* __restrict__ x,          // [B, L, C_IN]
    const float* __restrict__ conv_w,     // [73, 6, 3]
    const float* __restrict__ conv_b,     // [73]
    const float* __restrict__ leftout_w,  // [1, 6, 3]
    const float* __restrict__ leftout_b,  // [1]
    float* __restrict__ out)              // [B, L, 512]
{
    __shared__ float xs[C_IN][RPAD];
    __shared__ __align__(16) float buf[2][CHUNK][D_MODEL];  // 32 KB double-buffered out-tile

    const int tid = threadIdx.x;
    const int b   = blockIdx.x / NTB;
    const int tb  = blockIdx.x % NTB;
    const int t0  = tb * TB;

    // Stage x rows [t0-16, t0+TB] (circular) into LDS, transposed [ch][row].
    const float* xb = x + (size_t)b * L_SZ * C_IN;
    for (int i = tid; i < ROWS * C_IN; i += 512) {
        int r = i / C_IN, c = i - r * C_IN;
        int g = t0 - 16 + r;
        if (g < 0)      g += L_SZ;
        if (g >= L_SZ)  g -= L_SZ;
        xs[c][r] = xb[(size_t)g * C_IN + c];
    }
    __syncthreads();

    // Per-thread output column d: ch = d/73, o = d%73 (d==511 -> leftout).
    const int d = tid;
    int ch;
    const float* wsrc;
    float bias;
    if (d < C_IN * KERNELS) {
        ch = d / KERNELS;
        int o = d - ch * KERNELS;
        wsrc = conv_w + o * 18;
        bias = conv_b[o];
    } else {
        ch = C_IN - 1;
        wsrc = leftout_w;
        bias = leftout_b[0];
    }
    const float* __restrict__ row = &xs[ch][0];

    // FIR weights by row-offset j (0 = oldest = row t-16): k=j%3, m=(15+k-j)/3.
    float wreg[18];
    #pragma unroll
    for (int j = 0; j < 18; ++j) {
        int k = j % 3;
        int m = (15 + k - j) / 3;
        wreg[j] = wsrc[m * 3 + k];
    }

    const bool first = (tb == 0), last = (tb == NTB - 1);
    float4* outv = (float4*)(out + ((size_t)b * L_SZ + t0) * D_MODEL);

    // Sliding register window over staged rows; results round-trip through
    // buf[] so stores are wide and block-sequential (fill-kernel pattern).
    float win[18];
    #pragma unroll
    for (int j = 0; j < 17; ++j) win[j] = row[j];

    #pragma unroll
    for (int c = 0; c < NCHUNK; ++c) {
        #pragma unroll
        for (int i = 0; i < CHUNK; ++i) {
            const int tl = c * CHUNK + i;
            win[(tl + 17) % 18] = row[tl + 17];   // slide (keeps invariant on all paths)
            float acc = bias;
            if ((first && tl < 16) || (last && tl == TB - 1)) {
                // masked edge row (wrap + validity), block-uniform branch
                #pragma unroll
                for (int k = 0; k < 3; ++k) {
                    int tt = t0 + tl + k - 1;
                    if (tt < 0)      tt += L_SZ;
                    if (tt >= L_SZ)  tt -= L_SZ;
                    if (tt >= M_TAPS * TAO) {
                        int lt = tl + 15 + k;
                        #pragma unroll
                        for (int m = 0; m < 6; ++m)
                            acc = fmaf(row[lt - 3 * m], wreg[15 + k - 3 * m], acc);
                    }
                }
            } else {
                #pragma unroll
                for (int j = 0; j < 18; ++j)
                    acc = fmaf(win[(tl + j) % 18], wreg[j], acc);
            }
            buf[c & 1][i][d] = acc;
        }
        // Barrier WITHOUT vmcnt drain: LDS ordering only; global stores from
        // previous chunks stay in flight (T4 counted-wait discipline).
        __builtin_amdgcn_sched_barrier(0);
        asm volatile("s_waitcnt lgkmcnt(0)" ::: "memory");
        __builtin_amdgcn_sched_barrier(0);
        __builtin_amdgcn_s_barrier();
        __builtin_amdgcn_sched_barrier(0);

        const float4* bv = (const float4*)&buf[c & 1][0][0];
        float4 v0 = bv[tid];
        float4 v1 = bv[tid + 512];
        outv[c * 1024 + tid]       = v0;   // block writes sequential 16 KB/chunk
        outv[c * 1024 + tid + 512] = v1;
    }
}

extern "C" void kernel_launch(void* const* d_in, const int* in_sizes, int n_in,
                              void* d_out, int out_size, void* d_ws, size_t ws_size,
                              hipStream_t stream) {
    const float* x          = (const float*)d_in[0];
    const float* conv_w     = (const float*)d_in[1];
    const float* conv_b     = (const float*)d_in[2];
    const float* leftout_w  = (const float*)d_in[3];
    const float* leftout_b  = (const float*)d_in[4];
    float* out = (float*)d_out;

    dim3 grid(B_SZ * NTB);   // 2048 blocks
    trc_conv_kernel<<<grid, 512, 0, stream>>>(x, conv_w, conv_b,
                                              leftout_w, leftout_b, out);
}